// Round 5
// baseline (244.588 us; speedup 1.0000x reference)
//
#include <hip/hip_runtime.h>
#include <math.h>

#define HDIM 4096
#define THREADS 256
#define NC 16            // chunks/row for one wave: 16 × (64 lanes × f4) = 4096
#define EPSV 1e-6f

typedef float f4 __attribute__((ext_vector_type(4)));

__device__ __forceinline__ float waveSum(float v) {
    #pragma unroll
    for (int o = 32; o > 0; o >>= 1) v += __shfl_xor(v, o);
    return v;
}
__device__ __forceinline__ float waveMax(float v) {
    #pragma unroll
    for (int o = 32; o > 0; o >>= 1) v = fmaxf(v, __shfl_xor(v, o));
    return v;
}
__device__ __forceinline__ void runBreak() {
    __builtin_amdgcn_sched_barrier(0);   // keep per-stream store runs contiguous
}

// One WAVE per row (no LDS, no __syncthreads). Whole row held in registers so
// every output stream is written as one 16KB contiguous burst of 16 f4 stores
// -> long per-stream DRAM runs instead of 1KB round-robin over 9 streams.
__global__ __launch_bounds__(THREADS, 4) void fused_add_rmsnorm_quant(
    const float* __restrict__ x1, const float* __restrict__ x2,
    const float* __restrict__ w,  const float* __restrict__ sm,
    float* __restrict__ out, const long long N, const long long R)
{
    const int tid  = threadIdx.x;
    const int lane = tid & 63;
    const int wid  = tid >> 6;
    const long long row  = (long long)blockIdx.x * 4 + wid;
    const long long base = row * (long long)HDIM;
    const int colb = lane * 4;

    // ---- output layout: 10 outputs concatenated flat, all f32 ----
    float* out_q   = out;                 // yOut        [N]
    float* out_x   = out + N;             // xOut        [N]
    float* out_s1  = out + 2 * N;         // scale1Out   [R]
    float* out_y   = out + 2 * N + R;     // y1_flat     [N]
    float* out_xb  = out + 3 * N + R;     // xOut1       [N]
    float* out_q2  = out + 4 * N + R;     // yOut2       [N]
    float* out_s2  = out + 5 * N + R;     // scale1Out2  [R]
    float* out_x3  = out + 5 * N + 2 * R; // xOut3       [N]
    float* out_q3  = out + 6 * N + 2 * R; // yOut3       [N]
    float* out_s3  = out + 7 * N + 2 * R; // scale1Out3  [R]

    f4 xv[NC];          // the full row (64 VGPR) — everything else derives
    float ss = 0.f, mW = 0.f, mSm = 0.f;

    // ---- pass 1: grouped 4KB read runs, add, row statistics ----
    #pragma unroll
    for (int h = 0; h < 4; ++h) {
        f4 a[4], b[4];
        #pragma unroll
        for (int c = 0; c < 4; ++c)
            a[c] = __builtin_nontemporal_load(
                reinterpret_cast<const f4*>(x1 + base + (h*4 + c)*256 + colb));
        #pragma unroll
        for (int c = 0; c < 4; ++c)
            b[c] = __builtin_nontemporal_load(
                reinterpret_cast<const f4*>(x2 + base + (h*4 + c)*256 + colb));
        #pragma unroll
        for (int c = 0; c < 4; ++c) {
            const int col = (h*4 + c)*256 + colb;
            const f4 wv  = *reinterpret_cast<const f4*>(w  + col);
            const f4 smv = *reinterpret_cast<const f4*>(sm + col);
            const f4 x = a[c] + b[c];
            xv[h*4 + c] = x;
            #pragma unroll
            for (int j = 0; j < 4; ++j) {
                const float t = x[j] * wv[j];      // y = t*inv
                ss += x[j] * x[j];
                mW  = fmaxf(mW,  fabsf(t));
                mSm = fmaxf(mSm, fabsf(t * smv[j]));
            }
        }
    }

    // ---- x-streams: three 16KB bursts (independent of the reduction) ----
    runBreak();
    #pragma unroll
    for (int c = 0; c < NC; ++c)
        __builtin_nontemporal_store(xv[c],
            reinterpret_cast<f4*>(out_x  + base + c*256 + colb));
    runBreak();
    #pragma unroll
    for (int c = 0; c < NC; ++c)
        __builtin_nontemporal_store(xv[c],
            reinterpret_cast<f4*>(out_xb + base + c*256 + colb));
    runBreak();
    #pragma unroll
    for (int c = 0; c < NC; ++c)
        __builtin_nontemporal_store(xv[c],
            reinterpret_cast<f4*>(out_x3 + base + c*256 + colb));
    runBreak();

    // ---- wave-only reduction (no barrier anywhere) ----
    ss  = waveSum(ss);
    mW  = waveMax(mW);
    mSm = waveMax(mSm);

    const float inv    = 1.0f / sqrtf(ss * (1.0f / HDIM) + EPSV);
    const float scale1 = (inv * mSm) * (1.0f / 127.0f);
    const float scale3 = (inv * mW)  * (1.0f / 127.0f);
    const float rs1 = 1.0f / scale1;
    const float rs3 = 1.0f / scale3;

    // ---- q: 16KB burst ----
    #pragma unroll
    for (int c = 0; c < NC; ++c) {
        const int col = c*256 + colb;
        const f4 wv  = *reinterpret_cast<const f4*>(w  + col);
        const f4 smv = *reinterpret_cast<const f4*>(sm + col);
        f4 qf;
        #pragma unroll
        for (int j = 0; j < 4; ++j)
            qf[j] = rintf(xv[c][j] * inv * wv[j] * smv[j] * rs1);
        __builtin_nontemporal_store(qf, reinterpret_cast<f4*>(out_q + base + col));
    }
    runBreak();
    // ---- y: 16KB burst ----
    #pragma unroll
    for (int c = 0; c < NC; ++c) {
        const int col = c*256 + colb;
        const f4 wv = *reinterpret_cast<const f4*>(w + col);
        f4 yq;
        #pragma unroll
        for (int j = 0; j < 4; ++j)
            yq[j] = xv[c][j] * inv * wv[j];
        __builtin_nontemporal_store(yq, reinterpret_cast<f4*>(out_y + base + col));
    }
    runBreak();
    // ---- q2 (identical values to q, recomputed): 16KB burst ----
    #pragma unroll
    for (int c = 0; c < NC; ++c) {
        const int col = c*256 + colb;
        const f4 wv  = *reinterpret_cast<const f4*>(w  + col);
        const f4 smv = *reinterpret_cast<const f4*>(sm + col);
        f4 qf;
        #pragma unroll
        for (int j = 0; j < 4; ++j)
            qf[j] = rintf(xv[c][j] * inv * wv[j] * smv[j] * rs1);
        __builtin_nontemporal_store(qf, reinterpret_cast<f4*>(out_q2 + base + col));
    }
    runBreak();
    // ---- q3: 16KB burst ----
    #pragma unroll
    for (int c = 0; c < NC; ++c) {
        const int col = c*256 + colb;
        const f4 wv = *reinterpret_cast<const f4*>(w + col);
        f4 q3;
        #pragma unroll
        for (int j = 0; j < 4; ++j)
            q3[j] = rintf(xv[c][j] * inv * wv[j] * rs3);
        __builtin_nontemporal_store(q3, reinterpret_cast<f4*>(out_q3 + base + col));
    }

    if (lane == 0) {
        out_s1[row] = scale1;
        out_s2[row] = scale1;
        out_s3[row] = scale3;
    }
}

extern "C" void kernel_launch(void* const* d_in, const int* in_sizes, int n_in,
                              void* d_out, int out_size, void* d_ws, size_t ws_size,
                              hipStream_t stream) {
    const float* x1 = (const float*)d_in[0];
    const float* x2 = (const float*)d_in[1];
    const float* w  = (const float*)d_in[2];
    const float* sm = (const float*)d_in[3];
    float* out = (float*)d_out;

    const long long N = (long long)in_sizes[0];   // 2*4096*4096
    const long long R = N / HDIM;                 // 8192 rows

    fused_add_rmsnorm_quant<<<dim3((unsigned)(R / 4)), dim3(THREADS), 0, stream>>>(
        x1, x2, w, sm, out, N, R);
}

// Round 6
// 220.376 us; speedup vs baseline: 1.1099x; 1.1099x over previous
//
#include <hip/hip_runtime.h>
#include <math.h>

#define HDIM 4096
#define THREADS 256
#define CHUNK 4          // HDIM / (THREADS * 4) float4 chunks per thread
#define EPSV 1e-6f

typedef float f4 __attribute__((ext_vector_type(4)));

__device__ __forceinline__ float waveSum(float v) {
    #pragma unroll
    for (int o = 32; o > 0; o >>= 1) v += __shfl_xor(v, o);
    return v;
}
__device__ __forceinline__ float waveMax(float v) {
    #pragma unroll
    for (int o = 32; o > 0; o >>= 1) v = fmaxf(v, __shfl_xor(v, o));
    return v;
}

// One block per row of 4096. R4 structure + per-stream CHUNK ROTATION:
// stream bases are exact multiples of 2^29 (+0/32K/64K), so same-index
// stores to different streams alias in HBM-channel/L2-set bits. Rotating
// the chunk (4KB apart) per stream makes temporally-adjacent stores hit
// different channels/sets. Same addresses written, different time order.
__global__ __launch_bounds__(THREADS) void fused_add_rmsnorm_quant(
    const float* __restrict__ x1, const float* __restrict__ x2,
    const float* __restrict__ w,  const float* __restrict__ sm,
    float* __restrict__ out, const long long N, const long long R)
{
    __shared__ float redS[4];
    __shared__ float redW[4];
    __shared__ float redM[4];

    const int tid  = threadIdx.x;
    const int wave = tid >> 6;
    const int lane = tid & 63;
    const long long row  = blockIdx.x;
    const long long base = row * (long long)HDIM;

    // ---- output layout: 10 outputs concatenated flat, all f32 ----
    float* out_q   = out;                 // yOut        [N]
    float* out_x   = out + N;             // xOut        [N]
    float* out_s1  = out + 2 * N;         // scale1Out   [R]
    float* out_y   = out + 2 * N + R;     // y1_flat     [N]
    float* out_xb  = out + 3 * N + R;     // xOut1       [N]
    float* out_q2  = out + 4 * N + R;     // yOut2       [N]
    float* out_x3  = out + 5 * N + 2 * R; // xOut3       [N]
    float* out_q3  = out + 6 * N + 2 * R; // yOut3       [N]
    float* out_s2  = out + 5 * N + R;     // scale1Out2  [R]
    float* out_s3  = out + 7 * N + 2 * R; // scale1Out3  [R]

    f4 xv[CHUNK];   // x1+x2 — the only state held across the barrier

    // ---- pass 1: load, add, row statistics ----
    float ss = 0.f, mW = 0.f, mSm = 0.f;
    #pragma unroll
    for (int c = 0; c < CHUNK; ++c) {
        const int col = c * (THREADS * 4) + tid * 4;
        const long long idx = base + col;
        const f4 a = __builtin_nontemporal_load(
            reinterpret_cast<const f4*>(x1 + idx));
        const f4 b = __builtin_nontemporal_load(
            reinterpret_cast<const f4*>(x2 + idx));
        const f4 wv  = *reinterpret_cast<const f4*>(w  + col);
        const f4 smv = *reinterpret_cast<const f4*>(sm + col);
        const f4 x = a + b;
        xv[c] = x;
        #pragma unroll
        for (int j = 0; j < 4; ++j) {
            const float t = x[j] * wv[j];     // y = t*inv
            ss += x[j] * x[j];
            mW  = fmaxf(mW,  fabsf(t));
            mSm = fmaxf(mSm, fabsf(t * smv[j]));
        }
    }

    // ---- x-streams, chunk-rotated per stream (all xv ready) ----
    #pragma unroll
    for (int c = 0; c < CHUNK; ++c) {
        const int c0 = c, c1 = (c + 1) & 3, c2 = (c + 2) & 3;
        __builtin_nontemporal_store(xv[c0], reinterpret_cast<f4*>(
            out_x  + base + c0 * (THREADS * 4) + tid * 4));
        __builtin_nontemporal_store(xv[c1], reinterpret_cast<f4*>(
            out_xb + base + c1 * (THREADS * 4) + tid * 4));
        __builtin_nontemporal_store(xv[c2], reinterpret_cast<f4*>(
            out_x3 + base + c2 * (THREADS * 4) + tid * 4));
    }

    ss  = waveSum(ss);
    mW  = waveMax(mW);
    mSm = waveMax(mSm);
    if (lane == 0) { redS[wave] = ss; redW[wave] = mW; redM[wave] = mSm; }
    __syncthreads();
    ss  = (redS[0] + redS[1]) + (redS[2] + redS[3]);
    mW  = fmaxf(fmaxf(redW[0], redW[1]), fmaxf(redW[2], redW[3]));
    mSm = fmaxf(fmaxf(redM[0], redM[1]), fmaxf(redM[2], redM[3]));

    const float inv    = 1.0f / sqrtf(ss * (1.0f / HDIM) + EPSV);
    const float scale1 = (inv * mSm) * (1.0f / 127.0f);
    const float scale3 = (inv * mW)  * (1.0f / 127.0f);
    const float rs1 = 1.0f / scale1;
    const float rs3 = 1.0f / scale3;

    // ---- pass 2: 4 streams, chunk-rotated per stream ----
    #pragma unroll
    for (int c = 0; c < CHUNK; ++c) {
        const int cq  = c;
        const int cy  = (c + 1) & 3;
        const int cq2 = (c + 2) & 3;
        const int cq3 = (c + 3) & 3;

        {   // q @ chunk cq
            const int col = cq * (THREADS * 4) + tid * 4;
            const f4 wv  = *reinterpret_cast<const f4*>(w  + col);
            const f4 smv = *reinterpret_cast<const f4*>(sm + col);
            f4 qf;
            #pragma unroll
            for (int j = 0; j < 4; ++j)
                qf[j] = rintf(xv[cq][j] * inv * wv[j] * smv[j] * rs1);
            __builtin_nontemporal_store(qf,
                reinterpret_cast<f4*>(out_q + base + col));
        }
        {   // y @ chunk cy
            const int col = cy * (THREADS * 4) + tid * 4;
            const f4 wv = *reinterpret_cast<const f4*>(w + col);
            f4 yq;
            #pragma unroll
            for (int j = 0; j < 4; ++j)
                yq[j] = xv[cy][j] * inv * wv[j];
            __builtin_nontemporal_store(yq,
                reinterpret_cast<f4*>(out_y + base + col));
        }
        {   // q2 @ chunk cq2
            const int col = cq2 * (THREADS * 4) + tid * 4;
            const f4 wv  = *reinterpret_cast<const f4*>(w  + col);
            const f4 smv = *reinterpret_cast<const f4*>(sm + col);
            f4 qf;
            #pragma unroll
            for (int j = 0; j < 4; ++j)
                qf[j] = rintf(xv[cq2][j] * inv * wv[j] * smv[j] * rs1);
            __builtin_nontemporal_store(qf,
                reinterpret_cast<f4*>(out_q2 + base + col));
        }
        {   // q3 @ chunk cq3
            const int col = cq3 * (THREADS * 4) + tid * 4;
            const f4 wv = *reinterpret_cast<const f4*>(w + col);
            f4 q3;
            #pragma unroll
            for (int j = 0; j < 4; ++j)
                q3[j] = rintf(xv[cq3][j] * inv * wv[j] * rs3);
            __builtin_nontemporal_store(q3,
                reinterpret_cast<f4*>(out_q3 + base + col));
        }
    }

    if (tid == 0) {
        out_s1[row] = scale1;
        out_s2[row] = scale1;
        out_s3[row] = scale3;
    }
}

extern "C" void kernel_launch(void* const* d_in, const int* in_sizes, int n_in,
                              void* d_out, int out_size, void* d_ws, size_t ws_size,
                              hipStream_t stream) {
    const float* x1 = (const float*)d_in[0];
    const float* x2 = (const float*)d_in[1];
    const float* w  = (const float*)d_in[2];
    const float* sm = (const float*)d_in[3];
    float* out = (float*)d_out;

    const long long N = (long long)in_sizes[0];   // 2*4096*4096
    const long long R = N / HDIM;                 // 8192 rows

    fused_add_rmsnorm_quant<<<dim3((unsigned)R), dim3(THREADS), 0, stream>>>(
        x1, x2, w, sm, out, N, R);
}